// Round 5
// baseline (762.017 us; speedup 1.0000x reference)
//
#include <hip/hip_runtime.h>
#include <math.h>

// Bloom attention block. Inputs/outputs fp32; bf16 MFMA internally.
// B=1, S=2048, HID=4096, NH=32, HD=128.
// Pipeline: fp32->bf16 convert -> QKV GEMM (writes Q/K compact + V transposed)
//           -> flash attention -> dense GEMM.
// GEMMs: ring-3 counted-vmcnt pipeline, BIG wave tiles for LDS-read reuse.
//   Rounds 2-4 proved the 128x48-wave structure is LDS-read-wall-bound
//   (~1400 cyc/tile LDS vs 931 MFMA; ordering hints null). Wave 128x96
//   (BM=256,BN=384) lifts FLOP per LDS byte 35->55 so the MFMA pipe is the
//   wall (1863 vs ~1650). Grid 32x8=256 = exactly 1 CU round. A-frags are
//   STREAMED (load a[m+1] under m's MFMAs) to keep VGPR ~235 (acc=192).
// Attn: QBLK=128 8-wave flash, XOR-swizzled K/V LDS, T14 reg-prefetch,
//   slope-computed alibi, mask only on diagonal tiles. (SGB pins removed:
//   round-4 showed the 1:1 pin exposes per-pair lgkm latency.)

typedef __attribute__((ext_vector_type(8))) short short8;
typedef __attribute__((ext_vector_type(4))) float floatx4;
typedef __attribute__((ext_vector_type(4))) unsigned short ushort4v;

#define S_LEN 2048
#define HID_DIM 4096
#define NHEADS 32
#define HDIM 128
#define QKV_N 12288
#define QK_STRIDE 8192            // compact [S][NH*256] Q/K buffer
#define INV_NORM 0.08838834764831845f  // 1/sqrt(128)

__device__ __forceinline__ unsigned short f2bf(float f) {
    union { float f; unsigned int i; } v; v.f = f;
    unsigned int u = v.i;
    return (unsigned short)((u + 0x7fffu + ((u >> 16) & 1u)) >> 16);
}

// async 16B/lane global->LDS (lds dest = wave-uniform base + lane*16)
typedef __attribute__((address_space(1))) unsigned int guint;
typedef __attribute__((address_space(3))) unsigned int luint;
__device__ __forceinline__ void gl_lds16(const unsigned short* g, unsigned short* l) {
    __builtin_amdgcn_global_load_lds((guint*)g, (luint*)l, 16, 0, 0);
}

// counted vmcnt waits (immediates must be literal)
__device__ __forceinline__ void wvm5() { asm volatile("s_waitcnt vmcnt(5)" ::: "memory"); }
__device__ __forceinline__ void wvm3() { asm volatile("s_waitcnt vmcnt(3)" ::: "memory"); }
__device__ __forceinline__ void wvm0() { asm volatile("s_waitcnt vmcnt(0)" ::: "memory"); }

__device__ __forceinline__ void phase_bar() {
    __builtin_amdgcn_s_barrier();
    __builtin_amdgcn_sched_barrier(0);   // nothing moves across the barrier
}

// barrier that does NOT drain vmcnt (keeps prefetch loads in flight)
__device__ __forceinline__ void bar_lgkm() {
    asm volatile("s_waitcnt lgkmcnt(0)" ::: "memory");
    __builtin_amdgcn_s_barrier();
    __builtin_amdgcn_sched_barrier(0);
}

// ---------------------------------------------------------------------------
// fp32 -> bf16 (RNE), 8 elems/thread, exact grids
// ---------------------------------------------------------------------------
__global__ __launch_bounds__(256) void cvt_bf16(
    const float* __restrict__ src, unsigned short* __restrict__ dst)
{
    size_t i = ((size_t)blockIdx.x * 256 + threadIdx.x) * 8;
    float4 x = *(const float4*)(src + i);
    float4 y = *(const float4*)(src + i + 4);
    union { unsigned u[4]; short8 s; } r;
    r.u[0] = (unsigned)f2bf(x.x) | ((unsigned)f2bf(x.y) << 16);
    r.u[1] = (unsigned)f2bf(x.z) | ((unsigned)f2bf(x.w) << 16);
    r.u[2] = (unsigned)f2bf(y.x) | ((unsigned)f2bf(y.y) << 16);
    r.u[3] = (unsigned)f2bf(y.z) | ((unsigned)f2bf(y.w) << 16);
    *(short8*)(dst + i) = r.s;
}

// ---------------------------------------------------------------------------
// GEMM: C[m][n] = sum_k A[m][k]*B[n][k] + bias[n]  (bf16 in).
// Tile BM x BN (both multiples of 128), BK=32, 512 threads (8 waves, 2 x 4),
// wave owns (BM/2)x(BN/4). Ring of 3 LDS buffers, prefetch distance 2,
// steady wait vmcnt(LPT) = one full tile still in flight.
// Rows are 32 bf16 = 64B = 4 chunks; physical chunk = logical ^ ((row>>1)&3)
// -> conflict-free b128 frag reads (verified round 2: conflicts 1.9e7 -> 0).
// compute(): B-frags held (NF regs), A-frags streamed 2-ahead under MFMAs.
// MODE 0: fp32 out [M][N].  MODE 1: QKV — Q/K to compact [S][8192] bf16,
// V written transposed to vt[h][d][s]; 16-col frags never cross a 128-col
// block boundary, so head/type are wave-uniform per frag.
// ---------------------------------------------------------------------------
template <int MODE, int BM, int BN>
__global__ __launch_bounds__(512, 2) void gemm_pipe(
    const unsigned short* __restrict__ A,
    const unsigned short* __restrict__ B,
    const float* __restrict__ bias,
    unsigned short* __restrict__ Cq,
    float* __restrict__ Cf,
    unsigned short* __restrict__ vt,
    int M, int N, int K)
{
    constexpr int BK = 32;
    constexpr int MF = BM / 32;             // m-frags per wave
    constexpr int NF = BN / 64;             // n-frags per wave
    constexpr int WR = BM / 2;              // rows per wave-row
    constexpr int WC = BN / 4;              // cols per wave-col
    constexpr int BUFSH = (BM + BN) * BK;   // ushorts per ring buffer
    constexpr int LA = BM / 128;            // A slabs (gl_lds per thread)
    constexpr int SB = BN / 128;            // B slabs
    constexpr int LPT = LA + SB;            // loads per thread per tile
    static_assert(MF % 2 == 0, "A-stream needs even MF");
    static_assert(BM % 128 == 0 && BN % 128 == 0, "slab staging");

    __shared__ unsigned short lds[3 * BUFSH];

    const int t = threadIdx.x;
    const int w = t >> 6, lane = t & 63, quad = lane >> 4, l15 = lane & 15;
    const int wr = w >> 2, wc = w & 3;

    // XCD-aware bijective swizzle (both grids have nwg % 8 == 0)
    const int gx = gridDim.x;
    const int nwg = gx * gridDim.y;
    const int wg = blockIdx.y * gx + blockIdx.x;
    const int swz = (wg & 7) * (nwg >> 3) + (wg >> 3);
    const int bx = swz % gx, by = swz / gx;
    const int mb = by * BM, nb = bx * BN;

    // staging source: lane covers row w*16 + (lane>>2) of each 128-row slab,
    // physical chunk lane&3 -> logical chunk (lane&3) ^ ((row>>1)&3)
    const int srow = w * 16 + (lane >> 2);
    const int schunk = (((lane & 3) ^ ((lane >> 3) & 3)) << 3);
    const unsigned short* pa = A + (size_t)(mb + srow) * K + schunk;
    const unsigned short* pb = B + (size_t)(nb + srow) * K + schunk;
    const int la_off = w * 512;              // ushort offsets, wave-uniform
    const int lb_off = BM * BK + w * 512;

    // fragment reads: row ≡ l15 (mod 16); physical chunk = quad ^ ((l15>>1)&3)
    const int fchunk = ((quad ^ ((l15 >> 1) & 3)) << 3);
    const int aoff = (wr * WR + l15) * BK + fchunk;
    const int boff = BM * BK + (wc * WC + l15) * BK + fchunk;

    floatx4 acc[MF][NF];
#pragma unroll
    for (int i = 0; i < MF; i++)
#pragma unroll
        for (int j = 0; j < NF; j++) acc[i][j] = (floatx4)0.0f;

    int kstage = 0;
    auto stage = [&](int bufi) {
        unsigned short* lb = &lds[bufi * BUFSH];
#pragma unroll
        for (int i = 0; i < LA; i++)
            gl_lds16(pa + kstage + (size_t)i * 128 * K, lb + la_off + i * 4096);
#pragma unroll
        for (int i = 0; i < SB; i++)
            gl_lds16(pb + kstage + (size_t)i * 128 * K, lb + lb_off + i * 4096);
        kstage += BK;
    };
    // B-frags resident, A-frags streamed 2-ahead under the MFMA groups
    auto compute = [&](int bufi) {
        const unsigned short* lt = &lds[bufi * BUFSH];
        short8 bfr[NF];
#pragma unroll
        for (int n = 0; n < NF; n++)
            bfr[n] = *(const short8*)&lt[boff + n * 16 * BK];
        short8 aA = *(const short8*)&lt[aoff];
#pragma unroll
        for (int m = 0; m < MF; m += 2) {
            short8 aB = *(const short8*)&lt[aoff + (m + 1) * 16 * BK];
            __builtin_amdgcn_s_setprio(1);
#pragma unroll
            for (int n = 0; n < NF; n++)
                acc[m][n] = __builtin_amdgcn_mfma_f32_16x16x32_bf16(aA, bfr[n], acc[m][n], 0, 0, 0);
            __builtin_amdgcn_s_setprio(0);
            if (m + 2 < MF)
                aA = *(const short8*)&lt[aoff + (m + 2) * 16 * BK];
            __builtin_amdgcn_s_setprio(1);
#pragma unroll
            for (int n = 0; n < NF; n++)
                acc[m + 1][n] = __builtin_amdgcn_mfma_f32_16x16x32_bf16(aB, bfr[n], acc[m + 1][n], 0, 0, 0);
            __builtin_amdgcn_s_setprio(0);
        }
    };

    const int NT = K / BK;   // 128

    // prologue: stage tiles 0,1 (2*LPT loads in flight)
    stage(0); stage(1);

    // steady: at step kt top, outstanding = {kt, kt+1} (2*LPT);
    // vmcnt(LPT) drains exactly tile kt. Buffer (kt+2)%3 holds tile kt-1,
    // whose reads finished before this step's barrier -> race-free.
    int bc = 0, bs = 2;
    for (int kt = 0; kt < NT; kt++) {
        if (kt < NT - 1) { if constexpr (LPT == 5) wvm5(); else wvm3(); }
        else wvm0();
        phase_bar();
        if (kt + 2 < NT) stage(bs);
        compute(bc);
        bc = (bc == 2) ? 0 : bc + 1;
        bs = (bs == 2) ? 0 : bs + 1;
    }

    // epilogue
    if (MODE == 1) {
#pragma unroll
        for (int j = 0; j < NF; j++) {
            int cb = nb + wc * WC + j * 16;    // wave-uniform, 16-aligned
            int h = cb / 384;
            int type = (cb >> 7) % 3;          // 0=Q 1=K 2=V
            int db = cb & 127;
            float bv = bias[cb + l15];
            if (type == 2) {
                // V -> vt[h][d][s], lane packs its 4 consecutive rows (8B store)
                unsigned short* vp = vt + ((size_t)h * HDIM + db + l15) * S_LEN;
#pragma unroll
                for (int m = 0; m < MF; m++) {
                    int rowbase = mb + wr * WR + m * 16 + quad * 4;
                    ushort4v pk;
#pragma unroll
                    for (int r = 0; r < 4; r++) pk[r] = f2bf(acc[m][j][r] + bv);
                    *(ushort4v*)&vp[rowbase] = pk;
                }
            } else {
                size_t colo = (size_t)h * 256 + type * 128 + db + l15;
#pragma unroll
                for (int m = 0; m < MF; m++) {
                    int rowbase = mb + wr * WR + m * 16 + quad * 4;
#pragma unroll
                    for (int r = 0; r < 4; r++)
                        Cq[(size_t)(rowbase + r) * QK_STRIDE + colo] =
                            f2bf(acc[m][j][r] + bv);
                }
            }
        }
    } else {
#pragma unroll
        for (int j = 0; j < NF; j++) {
            int col = nb + wc * WC + j * 16 + l15;
            float bv = bias[col];
#pragma unroll
            for (int m = 0; m < MF; m++) {
                int rowbase = mb + wr * WR + m * 16 + quad * 4;
#pragma unroll
                for (int r = 0; r < 4; r++)
                    Cf[(size_t)(rowbase + r) * N + col] = acc[m][j][r] + bv;
            }
        }
    }
}

// ---------------------------------------------------------------------------
// Flash attention, causal + alibi. One block per (head, 128-row q tile),
// 512 threads (8 waves x 16 q-rows). KV tile = 64 keys.
// K LDS [64][128] and V^T LDS [128][64] XOR-swizzled (idx ^= (row&7)<<3).
// T14 reg-prefetch of next K/V tile across raw lgkm-only barriers.
// alibi computed as slope*k (1 scalar load); causal mask only on the 2
// diagonal tiles. Longest-first dispatch.
// ---------------------------------------------------------------------------
__global__ __launch_bounds__(512, 2) void attn_flash(
    const unsigned short* __restrict__ qk,      // [S][8192] bf16
    const unsigned short* __restrict__ vt,      // [NH][128][S] bf16
    const float* __restrict__ alibi,            // [NH][S] fp32
    unsigned short* __restrict__ ctx)           // [S][4096] bf16
{
    __shared__ unsigned short k_lds[64 * 128];   // [key][d], XOR-swizzled
    __shared__ unsigned short vt_lds[128 * 64];  // [d][key], XOR-swizzled
    __shared__ unsigned short p_lds[8 * 16 * 72];

    int h = blockIdx.x;
    int qt = (int)gridDim.y - 1 - (int)blockIdx.y;  // longest blocks first
    int qb = qt * 128;
    int t = threadIdx.x;
    int w = t >> 6, lane = t & 63, quad = lane >> 4, l15 = lane & 15;
    int qoff = h * 256;
    float slope = alibi[h * S_LEN + 1];   // alibi[h][k] = slope*k exactly

    // Q fragments (A-layout) for this wave's 16 q rows, all 128 dims
    short8 qf[4];
    {
        int qrow = qb + w * 16 + l15;
        const unsigned short* qp = qk + (size_t)qrow * QK_STRIDE + qoff;
#pragma unroll
        for (int ks = 0; ks < 4; ks++)
            qf[ks] = *(const short8*)&qp[ks * 32 + quad * 8];
    }

    floatx4 o[8];
#pragma unroll
    for (int j = 0; j < 8; j++) o[j] = (floatx4)0.0f;
    float m_prev[4], l_prev[4];
#pragma unroll
    for (int r = 0; r < 4; r++) { m_prev[r] = -INFINITY; l_prev[r] = 0.0f; }

    // staging geometry (constant per thread); LDS idx pre-swizzled
    int krow[2], kcol[2], kidx[2], vdd[2], vch[2], vidx[2];
#pragma unroll
    for (int i = 0; i < 2; i++) {
        int idx = t + 512 * i;
        krow[i] = idx >> 4; kcol[i] = (idx & 15) * 8;
        kidx[i] = (krow[i] * 128 + kcol[i]) ^ ((krow[i] & 7) << 3);
        vdd[i]  = idx >> 3; vch[i] = (idx & 7) * 8;
        vidx[i] = (vdd[i] * 64 + vch[i]) ^ ((vdd[i] & 7) << 3);
    }
    short8 kreg[2], vreg[2];
    auto prefetch = [&](int tile) {
        int kb = tile * 64;
#pragma unroll
        for (int i = 0; i < 2; i++) {
            kreg[i] = *(const short8*)(qk + (size_t)(kb + krow[i]) * QK_STRIDE + qoff + 128 + kcol[i]);
            vreg[i] = *(const short8*)(vt + ((size_t)h * HDIM + vdd[i]) * S_LEN + kb + vch[i]);
        }
    };

    int ntiles = 2 * qt + 2;
    prefetch(0);
    for (int tile = 0; tile < ntiles; tile++) {
        bar_lgkm();            // all waves done reading prev K/V tile
        // write prefetched regs (compiler inserts vmcnt waits per reg)
#pragma unroll
        for (int i = 0; i < 2; i++) {
            *(short8*)&k_lds[kidx[i]]  = kreg[i];
            *(short8*)&vt_lds[vidx[i]] = vreg[i];
        }
        if (tile + 1 < ntiles) prefetch(tile + 1);  // in flight across barrier
        bar_lgkm();            // LDS writes visible to all waves
        int kb = tile * 64;

        // S = Q K^T (per wave: 16 q-rows x 64 keys)
        floatx4 s[4];
#pragma unroll
        for (int j = 0; j < 4; j++) s[j] = (floatx4)0.0f;
        __builtin_amdgcn_s_setprio(1);
#pragma unroll
        for (int ks = 0; ks < 4; ks++) {
#pragma unroll
            for (int j = 0; j < 4; j++) {
                int row = j * 16 + l15;
                short8 bfr = *(const short8*)&k_lds[(row * 128 + ks * 32 + quad * 8) ^ ((l15 & 7) << 3)];
                s[j] = __builtin_amdgcn_mfma_f32_16x16x32_bf16(qf[ks], bfr, s[j], 0, 0, 0);
            }
        }
        __builtin_amdgcn_s_setprio(0);

        // scale + alibi (slope*k); causal mask only on the 2 diagonal tiles
        float sv[4][4];
        bool need_mask = (tile >= ntiles - 2);
#pragma unroll
        for (int j = 0; j < 4; j++) {
            int kcol2 = kb + j * 16 + l15;
            float al = slope * (float)kcol2;
#pragma unroll
            for (int r = 0; r < 4; r++) {
                float x = s[j][r] * INV_NORM + al;
                if (need_mask) {
                    int qrow = qb + w * 16 + quad * 4 + r;
                    x = (kcol2 <= qrow) ? x : -INFINITY;
                }
                sv[j][r] = x;
            }
        }

        // online softmax per q-row (rows live in one 16-lane group)
        float p[4][4];
#pragma unroll
        for (int r = 0; r < 4; r++) {
            float mt = fmaxf(fmaxf(sv[0][r], sv[1][r]), fmaxf(sv[2][r], sv[3][r]));
#pragma unroll
            for (int off = 1; off < 16; off <<= 1)
                mt = fmaxf(mt, __shfl_xor(mt, off, 64));
            float m_new = fmaxf(m_prev[r], mt);
            float alpha = __expf(m_prev[r] - m_new);   // exp(-inf)=0 first tile
            float rs = 0.0f;
#pragma unroll
            for (int j = 0; j < 4; j++) {
                float pv = __expf(sv[j][r] - m_new);   // masked -> exp(-inf)=0
                p[j][r] = pv;
                rs += pv;
            }
#pragma unroll
            for (int off = 1; off < 16; off <<= 1)
                rs += __shfl_xor(rs, off, 64);
            l_prev[r] = l_prev[r] * alpha + rs;
            m_prev[r] = m_new;
#pragma unroll
            for (int j = 0; j < 8; j++) o[j][r] *= alpha;
        }

        // P (C-layout) -> LDS -> A-layout fragments (per-wave region)
        {
            unsigned short* pb = &p_lds[w * 16 * 72];
#pragma unroll
            for (int j = 0; j < 4; j++)
#pragma unroll
                for (int r = 0; r < 4; r++)
                    pb[(quad * 4 + r) * 72 + j * 16 + l15] = f2bf(p[j][r]);
        }
        {
            const unsigned short* pb = &p_lds[w * 16 * 72];
            __builtin_amdgcn_s_setprio(1);
#pragma unroll
            for (int ks = 0; ks < 2; ks++) {
                short8 ap = *(const short8*)&pb[l15 * 72 + ks * 32 + quad * 8];
#pragma unroll
                for (int j = 0; j < 8; j++) {
                    int row = j * 16 + l15;
                    short8 bv = *(const short8*)&vt_lds[(row * 64 + ks * 32 + quad * 8) ^ ((l15 & 7) << 3)];
                    o[j] = __builtin_amdgcn_mfma_f32_16x16x32_bf16(ap, bv, o[j], 0, 0, 0);
                }
            }
            __builtin_amdgcn_s_setprio(0);
        }
    }

    // normalize and store ctx in [S][HID] layout (head h at cols h*128..)
#pragma unroll
    for (int r = 0; r < 4; r++) {
        float linv = 1.0f / l_prev[r];
        int qrow = qb + w * 16 + quad * 4 + r;
        unsigned short* op = ctx + (size_t)qrow * HID_DIM + h * HDIM;
#pragma unroll
        for (int j = 0; j < 8; j++)
            op[j * 16 + l15] = f2bf(o[j][r] * linv);
    }
}

extern "C" void kernel_launch(void* const* d_in, const int* in_sizes, int n_in,
                              void* d_out, int out_size, void* d_ws, size_t ws_size,
                              hipStream_t stream) {
    const float* hidden  = (const float*)d_in[0];  // [1,2048,4096] fp32
    const float* alibi   = (const float*)d_in[1];  // [32,1,2048]   fp32
    const float* w_qkv   = (const float*)d_in[2];  // [12288,4096]  fp32
    const float* b_qkv   = (const float*)d_in[3];  // [12288]       fp32
    const float* w_dense = (const float*)d_in[4];  // [4096,4096]   fp32
    const float* b_dense = (const float*)d_in[5];  // [4096]        fp32
    float* out = (float*)d_out;                    // [2048,4096]   fp32

    // ws layout (ushort elements), with overlays (stream order makes it safe):
    //   [0 .. 50.3M)   wq_bf  (w_qkv bf16)      -- reused for wd_bf after QKV
    //   [+16.8M)       fused  [S][8192] Q/K compact
    //   [+8.4M)        vt     [NH][128][S]
    //   [+8.4M)        hbf    (hidden bf16)     -- reused as ctx after QKV
    unsigned short* ws    = (unsigned short*)d_ws;
    unsigned short* wq_bf = ws;
    unsigned short* fused = ws + (size_t)50331648;
    unsigned short* vt    = fused + (size_t)S_LEN * QK_STRIDE;      // +16,777,216
    unsigned short* hbf   = vt + (size_t)NHEADS * HDIM * S_LEN;     // +8,388,608
    unsigned short* ctx   = hbf;   // overlay: hbf dead after QKV GEMM
    unsigned short* wd_bf = wq_bf; // overlay: wq_bf dead after QKV GEMM

    dim3 blk(256), blk512(512);
    // converts (8 elems/thread, exact grids)
    cvt_bf16<<<dim3(4096),  blk, 0, stream>>>(hidden,  hbf);     // 8,388,608
    cvt_bf16<<<dim3(24576), blk, 0, stream>>>(w_qkv,   wq_bf);   // 50,331,648
    // QKV projection. 256x384 tiles -> grid 32x8 = 256 = exactly 1 CU round
    gemm_pipe<1, 256, 384><<<dim3(QKV_N / 384, S_LEN / 256), blk512, 0, stream>>>(
        hbf, wq_bf, b_qkv, fused, nullptr, vt, S_LEN, QKV_N, HID_DIM);
    // attention (8 waves, 128 q-rows/block; longest q-tiles dispatch first)
    attn_flash<<<dim3(NHEADS, S_LEN / 128), blk512, 0, stream>>>(fused, vt, alibi, ctx);
    // dense weight convert (overlays wq_bf, safe after QKV GEMM)
    cvt_bf16<<<dim3(8192), blk, 0, stream>>>(w_dense, wd_bf);    // 16,777,216
    // output projection (fp32 out). 128x256 tiles, grid 16x16 = 256 (exact fill)
    gemm_pipe<0, 128, 256><<<dim3(HID_DIM / 256, S_LEN / 128), blk512, 0, stream>>>(
        ctx, wd_bf, b_dense, nullptr, out, nullptr, S_LEN, HID_DIM, HID_DIM);
}

// Round 6
// 685.242 us; speedup vs baseline: 1.1120x; 1.1120x over previous
//
#include <hip/hip_runtime.h>
#include <math.h>

// Bloom attention block. Inputs/outputs fp32; bf16 MFMA internally.
// B=1, S=2048, HID=4096, NH=32, HD=128.
// Pipeline: fp32->bf16 convert -> QKV GEMM (writes Q/K compact + V transposed)
//           -> flash attention -> dense GEMM.
// GEMMs: ring-3 counted-vmcnt pipeline, 256x384 tile (QKV) for MFMA-side
//   balance. ROUND-5 LESSON: XCD swizzle with ROW-major decode gave each XCD
//   one A-panel x ALL B-panels -> 98 MB/XCD of un-reusable B stream through a
//   4 MB L2 (FETCH 781 MB, traffic-bound, 249 us). COLUMN-major decode gives
//   each XCD a 4-wide B-column band x all A-rows: per-XCD fill 29 MB
//   (B panels shared 8-way, A panels 4-way in L2). Predicted FETCH <300 MB.
// Attn: QBLK=128 8-wave flash, XOR-swizzled K/V LDS, T14 reg-prefetch,
//   slope-computed alibi, mask only on diagonal tiles. (Unchanged this round.)

typedef __attribute__((ext_vector_type(8))) short short8;
typedef __attribute__((ext_vector_type(4))) float floatx4;
typedef __attribute__((ext_vector_type(4))) unsigned short ushort4v;

#define S_LEN 2048
#define HID_DIM 4096
#define NHEADS 32
#define HDIM 128
#define QKV_N 12288
#define QK_STRIDE 8192            // compact [S][NH*256] Q/K buffer
#define INV_NORM 0.08838834764831845f  // 1/sqrt(128)

__device__ __forceinline__ unsigned short f2bf(float f) {
    union { float f; unsigned int i; } v; v.f = f;
    unsigned int u = v.i;
    return (unsigned short)((u + 0x7fffu + ((u >> 16) & 1u)) >> 16);
}

// async 16B/lane global->LDS (lds dest = wave-uniform base + lane*16)
typedef __attribute__((address_space(1))) unsigned int guint;
typedef __attribute__((address_space(3))) unsigned int luint;
__device__ __forceinline__ void gl_lds16(const unsigned short* g, unsigned short* l) {
    __builtin_amdgcn_global_load_lds((guint*)g, (luint*)l, 16, 0, 0);
}

// counted vmcnt waits (immediates must be literal)
__device__ __forceinline__ void wvm5() { asm volatile("s_waitcnt vmcnt(5)" ::: "memory"); }
__device__ __forceinline__ void wvm3() { asm volatile("s_waitcnt vmcnt(3)" ::: "memory"); }
__device__ __forceinline__ void wvm0() { asm volatile("s_waitcnt vmcnt(0)" ::: "memory"); }

__device__ __forceinline__ void phase_bar() {
    __builtin_amdgcn_s_barrier();
    __builtin_amdgcn_sched_barrier(0);   // nothing moves across the barrier
}

// barrier that does NOT drain vmcnt (keeps prefetch loads in flight)
__device__ __forceinline__ void bar_lgkm() {
    asm volatile("s_waitcnt lgkmcnt(0)" ::: "memory");
    __builtin_amdgcn_s_barrier();
    __builtin_amdgcn_sched_barrier(0);
}

// ---------------------------------------------------------------------------
// fp32 -> bf16 (RNE), 8 elems/thread, exact grids
// ---------------------------------------------------------------------------
__global__ __launch_bounds__(256) void cvt_bf16(
    const float* __restrict__ src, unsigned short* __restrict__ dst)
{
    size_t i = ((size_t)blockIdx.x * 256 + threadIdx.x) * 8;
    float4 x = *(const float4*)(src + i);
    float4 y = *(const float4*)(src + i + 4);
    union { unsigned u[4]; short8 s; } r;
    r.u[0] = (unsigned)f2bf(x.x) | ((unsigned)f2bf(x.y) << 16);
    r.u[1] = (unsigned)f2bf(x.z) | ((unsigned)f2bf(x.w) << 16);
    r.u[2] = (unsigned)f2bf(y.x) | ((unsigned)f2bf(y.y) << 16);
    r.u[3] = (unsigned)f2bf(y.z) | ((unsigned)f2bf(y.w) << 16);
    *(short8*)(dst + i) = r.s;
}

// ---------------------------------------------------------------------------
// GEMM: C[m][n] = sum_k A[m][k]*B[n][k] + bias[n]  (bf16 in).
// Tile BM x BN (both multiples of 128), BK=32, 512 threads (8 waves, 2 x 4),
// wave owns (BM/2)x(BN/4). Ring of 3 LDS buffers, prefetch distance 2,
// steady wait vmcnt(LPT) = one full tile still in flight.
// Rows are 32 bf16 = 64B = 4 chunks; physical chunk = logical ^ ((row>>1)&3)
// -> conflict-free b128 frag reads (verified round 2: conflicts 1.9e7 -> 0).
// compute(): B-frags held (NF regs), A-frags streamed 2-ahead under MFMAs.
// Block mapping: XCD-contiguous swizzled id, COLUMN-major decode -> each XCD
// owns a B-column band across all A-rows (L2-resident working set).
// MODE 0: fp32 out [M][N].  MODE 1: QKV — Q/K to compact [S][8192] bf16,
// V written transposed to vt[h][d][s]; 16-col frags never cross a 128-col
// block boundary, so head/type are wave-uniform per frag.
// ---------------------------------------------------------------------------
template <int MODE, int BM, int BN>
__global__ __launch_bounds__(512, 2) void gemm_pipe(
    const unsigned short* __restrict__ A,
    const unsigned short* __restrict__ B,
    const float* __restrict__ bias,
    unsigned short* __restrict__ Cq,
    float* __restrict__ Cf,
    unsigned short* __restrict__ vt,
    int M, int N, int K)
{
    constexpr int BK = 32;
    constexpr int MF = BM / 32;             // m-frags per wave
    constexpr int NF = BN / 64;             // n-frags per wave
    constexpr int WR = BM / 2;              // rows per wave-row
    constexpr int WC = BN / 4;              // cols per wave-col
    constexpr int BUFSH = (BM + BN) * BK;   // ushorts per ring buffer
    constexpr int LA = BM / 128;            // A slabs (gl_lds per thread)
    constexpr int SB = BN / 128;            // B slabs
    constexpr int LPT = LA + SB;            // loads per thread per tile
    static_assert(MF % 2 == 0, "A-stream needs even MF");
    static_assert(BM % 128 == 0 && BN % 128 == 0, "slab staging");

    __shared__ unsigned short lds[3 * BUFSH];

    const int t = threadIdx.x;
    const int w = t >> 6, lane = t & 63, quad = lane >> 4, l15 = lane & 15;
    const int wr = w >> 2, wc = w & 3;

    // XCD-aware bijective swizzle (nwg % 8 == 0). XCD x (= wg&7 under
    // round-robin dispatch) gets swz in [x*nwg/8, (x+1)*nwg/8).
    // COLUMN-major decode: that range = a contiguous bx band x all by
    // -> per-XCD L2 working set = small B band + shared A panels.
    const int gx = gridDim.x;
    const int gy = gridDim.y;
    const int nwg = gx * gy;
    const int wg = blockIdx.y * gx + blockIdx.x;
    const int swz = (wg & 7) * (nwg >> 3) + (wg >> 3);
    const int bx = swz / gy, by = swz % gy;
    const int mb = by * BM, nb = bx * BN;

    // staging source: lane covers row w*16 + (lane>>2) of each 128-row slab,
    // physical chunk lane&3 -> logical chunk (lane&3) ^ ((row>>1)&3)
    const int srow = w * 16 + (lane >> 2);
    const int schunk = (((lane & 3) ^ ((lane >> 3) & 3)) << 3);
    const unsigned short* pa = A + (size_t)(mb + srow) * K + schunk;
    const unsigned short* pb = B + (size_t)(nb + srow) * K + schunk;
    const int la_off = w * 512;              // ushort offsets, wave-uniform
    const int lb_off = BM * BK + w * 512;

    // fragment reads: row ≡ l15 (mod 16); physical chunk = quad ^ ((l15>>1)&3)
    const int fchunk = ((quad ^ ((l15 >> 1) & 3)) << 3);
    const int aoff = (wr * WR + l15) * BK + fchunk;
    const int boff = BM * BK + (wc * WC + l15) * BK + fchunk;

    floatx4 acc[MF][NF];
#pragma unroll
    for (int i = 0; i < MF; i++)
#pragma unroll
        for (int j = 0; j < NF; j++) acc[i][j] = (floatx4)0.0f;

    int kstage = 0;
    auto stage = [&](int bufi) {
        unsigned short* lb = &lds[bufi * BUFSH];
#pragma unroll
        for (int i = 0; i < LA; i++)
            gl_lds16(pa + kstage + (size_t)i * 128 * K, lb + la_off + i * 4096);
#pragma unroll
        for (int i = 0; i < SB; i++)
            gl_lds16(pb + kstage + (size_t)i * 128 * K, lb + lb_off + i * 4096);
        kstage += BK;
    };
    // B-frags resident, A-frags streamed 2-ahead under the MFMA groups
    auto compute = [&](int bufi) {
        const unsigned short* lt = &lds[bufi * BUFSH];
        short8 bfr[NF];
#pragma unroll
        for (int n = 0; n < NF; n++)
            bfr[n] = *(const short8*)&lt[boff + n * 16 * BK];
        short8 aA = *(const short8*)&lt[aoff];
#pragma unroll
        for (int m = 0; m < MF; m += 2) {
            short8 aB = *(const short8*)&lt[aoff + (m + 1) * 16 * BK];
            __builtin_amdgcn_s_setprio(1);
#pragma unroll
            for (int n = 0; n < NF; n++)
                acc[m][n] = __builtin_amdgcn_mfma_f32_16x16x32_bf16(aA, bfr[n], acc[m][n], 0, 0, 0);
            __builtin_amdgcn_s_setprio(0);
            if (m + 2 < MF)
                aA = *(const short8*)&lt[aoff + (m + 2) * 16 * BK];
            __builtin_amdgcn_s_setprio(1);
#pragma unroll
            for (int n = 0; n < NF; n++)
                acc[m + 1][n] = __builtin_amdgcn_mfma_f32_16x16x32_bf16(aB, bfr[n], acc[m + 1][n], 0, 0, 0);
            __builtin_amdgcn_s_setprio(0);
        }
    };

    const int NT = K / BK;   // 128

    // prologue: stage tiles 0,1 (2*LPT loads in flight)
    stage(0); stage(1);

    // steady: at step kt top, outstanding = {kt, kt+1} (2*LPT);
    // vmcnt(LPT) drains exactly tile kt. Buffer (kt+2)%3 holds tile kt-1,
    // whose reads finished before this step's barrier -> race-free.
    int bc = 0, bs = 2;
    for (int kt = 0; kt < NT; kt++) {
        if (kt < NT - 1) { if constexpr (LPT == 5) wvm5(); else wvm3(); }
        else wvm0();
        phase_bar();
        if (kt + 2 < NT) stage(bs);
        compute(bc);
        bc = (bc == 2) ? 0 : bc + 1;
        bs = (bs == 2) ? 0 : bs + 1;
    }

    // epilogue
    if (MODE == 1) {
#pragma unroll
        for (int j = 0; j < NF; j++) {
            int cb = nb + wc * WC + j * 16;    // wave-uniform, 16-aligned
            int h = cb / 384;
            int type = (cb >> 7) % 3;          // 0=Q 1=K 2=V
            int db = cb & 127;
            float bv = bias[cb + l15];
            if (type == 2) {
                // V -> vt[h][d][s], lane packs its 4 consecutive rows (8B store)
                unsigned short* vp = vt + ((size_t)h * HDIM + db + l15) * S_LEN;
#pragma unroll
                for (int m = 0; m < MF; m++) {
                    int rowbase = mb + wr * WR + m * 16 + quad * 4;
                    ushort4v pk;
#pragma unroll
                    for (int r = 0; r < 4; r++) pk[r] = f2bf(acc[m][j][r] + bv);
                    *(ushort4v*)&vp[rowbase] = pk;
                }
            } else {
                size_t colo = (size_t)h * 256 + type * 128 + db + l15;
#pragma unroll
                for (int m = 0; m < MF; m++) {
                    int rowbase = mb + wr * WR + m * 16 + quad * 4;
#pragma unroll
                    for (int r = 0; r < 4; r++)
                        Cq[(size_t)(rowbase + r) * QK_STRIDE + colo] =
                            f2bf(acc[m][j][r] + bv);
                }
            }
        }
    } else {
#pragma unroll
        for (int j = 0; j < NF; j++) {
            int col = nb + wc * WC + j * 16 + l15;
            float bv = bias[col];
#pragma unroll
            for (int m = 0; m < MF; m++) {
                int rowbase = mb + wr * WR + m * 16 + quad * 4;
#pragma unroll
                for (int r = 0; r < 4; r++)
                    Cf[(size_t)(rowbase + r) * N + col] = acc[m][j][r] + bv;
            }
        }
    }
}

// ---------------------------------------------------------------------------
// Flash attention, causal + alibi. One block per (head, 128-row q tile),
// 512 threads (8 waves x 16 q-rows). KV tile = 64 keys.
// K LDS [64][128] and V^T LDS [128][64] XOR-swizzled (idx ^= (row&7)<<3).
// T14 reg-prefetch of next K/V tile across raw lgkm-only barriers.
// alibi computed as slope*k (1 scalar load); causal mask only on the 2
// diagonal tiles. Longest-first dispatch.
// ---------------------------------------------------------------------------
__global__ __launch_bounds__(512, 2) void attn_flash(
    const unsigned short* __restrict__ qk,      // [S][8192] bf16
    const unsigned short* __restrict__ vt,      // [NH][128][S] bf16
    const float* __restrict__ alibi,            // [NH][S] fp32
    unsigned short* __restrict__ ctx)           // [S][4096] bf16
{
    __shared__ unsigned short k_lds[64 * 128];   // [key][d], XOR-swizzled
    __shared__ unsigned short vt_lds[128 * 64];  // [d][key], XOR-swizzled
    __shared__ unsigned short p_lds[8 * 16 * 72];

    int h = blockIdx.x;
    int qt = (int)gridDim.y - 1 - (int)blockIdx.y;  // longest blocks first
    int qb = qt * 128;
    int t = threadIdx.x;
    int w = t >> 6, lane = t & 63, quad = lane >> 4, l15 = lane & 15;
    int qoff = h * 256;
    float slope = alibi[h * S_LEN + 1];   // alibi[h][k] = slope*k exactly

    // Q fragments (A-layout) for this wave's 16 q rows, all 128 dims
    short8 qf[4];
    {
        int qrow = qb + w * 16 + l15;
        const unsigned short* qp = qk + (size_t)qrow * QK_STRIDE + qoff;
#pragma unroll
        for (int ks = 0; ks < 4; ks++)
            qf[ks] = *(const short8*)&qp[ks * 32 + quad * 8];
    }

    floatx4 o[8];
#pragma unroll
    for (int j = 0; j < 8; j++) o[j] = (floatx4)0.0f;
    float m_prev[4], l_prev[4];
#pragma unroll
    for (int r = 0; r < 4; r++) { m_prev[r] = -INFINITY; l_prev[r] = 0.0f; }

    // staging geometry (constant per thread); LDS idx pre-swizzled
    int krow[2], kcol[2], kidx[2], vdd[2], vch[2], vidx[2];
#pragma unroll
    for (int i = 0; i < 2; i++) {
        int idx = t + 512 * i;
        krow[i] = idx >> 4; kcol[i] = (idx & 15) * 8;
        kidx[i] = (krow[i] * 128 + kcol[i]) ^ ((krow[i] & 7) << 3);
        vdd[i]  = idx >> 3; vch[i] = (idx & 7) * 8;
        vidx[i] = (vdd[i] * 64 + vch[i]) ^ ((vdd[i] & 7) << 3);
    }
    short8 kreg[2], vreg[2];
    auto prefetch = [&](int tile) {
        int kb = tile * 64;
#pragma unroll
        for (int i = 0; i < 2; i++) {
            kreg[i] = *(const short8*)(qk + (size_t)(kb + krow[i]) * QK_STRIDE + qoff + 128 + kcol[i]);
            vreg[i] = *(const short8*)(vt + ((size_t)h * HDIM + vdd[i]) * S_LEN + kb + vch[i]);
        }
    };

    int ntiles = 2 * qt + 2;
    prefetch(0);
    for (int tile = 0; tile < ntiles; tile++) {
        bar_lgkm();            // all waves done reading prev K/V tile
        // write prefetched regs (compiler inserts vmcnt waits per reg)
#pragma unroll
        for (int i = 0; i < 2; i++) {
            *(short8*)&k_lds[kidx[i]]  = kreg[i];
            *(short8*)&vt_lds[vidx[i]] = vreg[i];
        }
        if (tile + 1 < ntiles) prefetch(tile + 1);  // in flight across barrier
        bar_lgkm();            // LDS writes visible to all waves
        int kb = tile * 64;

        // S = Q K^T (per wave: 16 q-rows x 64 keys)
        floatx4 s[4];
#pragma unroll
        for (int j = 0; j < 4; j++) s[j] = (floatx4)0.0f;
        __builtin_amdgcn_s_setprio(1);
#pragma unroll
        for (int ks = 0; ks < 4; ks++) {
#pragma unroll
            for (int j = 0; j < 4; j++) {
                int row = j * 16 + l15;
                short8 bfr = *(const short8*)&k_lds[(row * 128 + ks * 32 + quad * 8) ^ ((l15 & 7) << 3)];
                s[j] = __builtin_amdgcn_mfma_f32_16x16x32_bf16(qf[ks], bfr, s[j], 0, 0, 0);
            }
        }
        __builtin_amdgcn_s_setprio(0);

        // scale + alibi (slope*k); causal mask only on the 2 diagonal tiles
        float sv[4][4];
        bool need_mask = (tile >= ntiles - 2);
#pragma unroll
        for (int j = 0; j < 4; j++) {
            int kcol2 = kb + j * 16 + l15;
            float al = slope * (float)kcol2;
#pragma unroll
            for (int r = 0; r < 4; r++) {
                float x = s[j][r] * INV_NORM + al;
                if (need_mask) {
                    int qrow = qb + w * 16 + quad * 4 + r;
                    x = (kcol2 <= qrow) ? x : -INFINITY;
                }
                sv[j][r] = x;
            }
        }

        // online softmax per q-row (rows live in one 16-lane group)
        float p[4][4];
#pragma unroll
        for (int r = 0; r < 4; r++) {
            float mt = fmaxf(fmaxf(sv[0][r], sv[1][r]), fmaxf(sv[2][r], sv[3][r]));
#pragma unroll
            for (int off = 1; off < 16; off <<= 1)
                mt = fmaxf(mt, __shfl_xor(mt, off, 64));
            float m_new = fmaxf(m_prev[r], mt);
            float alpha = __expf(m_prev[r] - m_new);   // exp(-inf)=0 first tile
            float rs = 0.0f;
#pragma unroll
            for (int j = 0; j < 4; j++) {
                float pv = __expf(sv[j][r] - m_new);   // masked -> exp(-inf)=0
                p[j][r] = pv;
                rs += pv;
            }
#pragma unroll
            for (int off = 1; off < 16; off <<= 1)
                rs += __shfl_xor(rs, off, 64);
            l_prev[r] = l_prev[r] * alpha + rs;
            m_prev[r] = m_new;
#pragma unroll
            for (int j = 0; j < 8; j++) o[j][r] *= alpha;
        }

        // P (C-layout) -> LDS -> A-layout fragments (per-wave region)
        {
            unsigned short* pb = &p_lds[w * 16 * 72];
#pragma unroll
            for (int j = 0; j < 4; j++)
#pragma unroll
                for (int r = 0; r < 4; r++)
                    pb[(quad * 4 + r) * 72 + j * 16 + l15] = f2bf(p[j][r]);
        }
        {
            const unsigned short* pb = &p_lds[w * 16 * 72];
            __builtin_amdgcn_s_setprio(1);
#pragma unroll
            for (int ks = 0; ks < 2; ks++) {
                short8 ap = *(const short8*)&pb[l15 * 72 + ks * 32 + quad * 8];
#pragma unroll
                for (int j = 0; j < 8; j++) {
                    int row = j * 16 + l15;
                    short8 bv = *(const short8*)&vt_lds[(row * 64 + ks * 32 + quad * 8) ^ ((l15 & 7) << 3)];
                    o[j] = __builtin_amdgcn_mfma_f32_16x16x32_bf16(ap, bv, o[j], 0, 0, 0);
                }
            }
            __builtin_amdgcn_s_setprio(0);
        }
    }

    // normalize and store ctx in [S][HID] layout (head h at cols h*128..)
#pragma unroll
    for (int r = 0; r < 4; r++) {
        float linv = 1.0f / l_prev[r];
        int qrow = qb + w * 16 + quad * 4 + r;
        unsigned short* op = ctx + (size_t)qrow * HID_DIM + h * HDIM;
#pragma unroll
        for (int j = 0; j < 8; j++)
            op[j * 16 + l15] = f2bf(o[j][r] * linv);
    }
}

extern "C" void kernel_launch(void* const* d_in, const int* in_sizes, int n_in,
                              void* d_out, int out_size, void* d_ws, size_t ws_size,
                              hipStream_t stream) {
    const float* hidden  = (const float*)d_in[0];  // [1,2048,4096] fp32
    const float* alibi   = (const float*)d_in[1];  // [32,1,2048]   fp32
    const float* w_qkv   = (const float*)d_in[2];  // [12288,4096]  fp32
    const float* b_qkv   = (const float*)d_in[3];  // [12288]       fp32
    const float* w_dense = (const float*)d_in[4];  // [4096,4096]   fp32
    const float* b_dense = (const float*)d_in[5];  // [4096]        fp32
    float* out = (float*)d_out;                    // [2048,4096]   fp32

    // ws layout (ushort elements), with overlays (stream order makes it safe):
    //   [0 .. 50.3M)   wq_bf  (w_qkv bf16)      -- reused for wd_bf after QKV
    //   [+16.8M)       fused  [S][8192] Q/K compact
    //   [+8.4M)        vt     [NH][128][S]
    //   [+8.4M)        hbf    (hidden bf16)     -- reused as ctx after QKV
    unsigned short* ws    = (unsigned short*)d_ws;
    unsigned short* wq_bf = ws;
    unsigned short* fused = ws + (size_t)50331648;
    unsigned short* vt    = fused + (size_t)S_LEN * QK_STRIDE;      // +16,777,216
    unsigned short* hbf   = vt + (size_t)NHEADS * HDIM * S_LEN;     // +8,388,608
    unsigned short* ctx   = hbf;   // overlay: hbf dead after QKV GEMM
    unsigned short* wd_bf = wq_bf; // overlay: wq_bf dead after QKV GEMM

    dim3 blk(256), blk512(512);
    // converts (8 elems/thread, exact grids)
    cvt_bf16<<<dim3(4096),  blk, 0, stream>>>(hidden,  hbf);     // 8,388,608
    cvt_bf16<<<dim3(24576), blk, 0, stream>>>(w_qkv,   wq_bf);   // 50,331,648
    // QKV projection. 256x384 tiles -> grid 32x8 = 256 = exactly 1 CU round
    gemm_pipe<1, 256, 384><<<dim3(QKV_N / 384, S_LEN / 256), blk512, 0, stream>>>(
        hbf, wq_bf, b_qkv, fused, nullptr, vt, S_LEN, QKV_N, HID_DIM);
    // attention (8 waves, 128 q-rows/block; longest q-tiles dispatch first)
    attn_flash<<<dim3(NHEADS, S_LEN / 128), blk512, 0, stream>>>(fused, vt, alibi, ctx);
    // dense weight convert (overlays wq_bf, safe after QKV GEMM)
    cvt_bf16<<<dim3(8192), blk, 0, stream>>>(w_dense, wd_bf);    // 16,777,216
    // output projection (fp32 out). 128x256 tiles, grid 16x16 = 256 (exact fill)
    gemm_pipe<0, 128, 256><<<dim3(HID_DIM / 256, S_LEN / 128), blk512, 0, stream>>>(
        ctx, wd_bf, b_dense, nullptr, out, nullptr, S_LEN, HID_DIM, HID_DIM);
}